// Round 5
// baseline (1152.880 us; speedup 1.0000x reference)
//
#include <hip/hip_runtime.h>
#include <hip/hip_bf16.h>
#include <math.h>

// CausalSelfAttention fused pipeline for MI355X (gfx950).
// B=4 T=2048 C=2048 H=16 HK=4 D=128 WIN=1024.
// R2: S^T trick, register-resident P, XOR-swizzled K/V, 32KB LDS.
// R3/R5: explicit pipelines regressed (occupancy loss / restructure cost).
// R6: R0 skeleton + XCD swizzle (FETCH 68.7->24.7MB, time flat -> not
// HBM-bound) + VALU cuts + launch fusions. 787us total, attn 180us.
// R7: occupancy play. Counters show MFMA 18% + VALU 27% + LDS ~25% with ~30%
// stall and near-zero overlap -> 3 waves/SIMD (VGPR 152) is too few. Fused
// per-tn streaming softmax with fixed optimistic reference max (m0=12,
// softmax shift-invariance) kills sfT[32]+pf[16] transients; PV per tn;
// rare rescale (of,l,m) AFTER the tile is uniform-correct. launch_bounds
// (256,4) caps VGPR at 128 -> 4 waves/SIMD.

using bf16 = __hip_bfloat16;
typedef __attribute__((ext_vector_type(8))) short bf16x8;
typedef __attribute__((ext_vector_type(4))) short bf16x4;
typedef __attribute__((ext_vector_type(4))) float f32x4;

constexpr int Bb = 4, Ts = 2048, Cc = 2048, NH = 16, NKV = 4, Dh = 128, WIN = 1024;
constexpr float EPS = 1.1920929e-07f;

__device__ __forceinline__ void gld16(void* lds, const void* g) {
  __builtin_amdgcn_global_load_lds(
      (__attribute__((address_space(1))) unsigned int*)((void*)g),
      (__attribute__((address_space(3))) unsigned int*)lds, 16, 0, 0);
}

__device__ __forceinline__ unsigned short bfbits(float f) {
  bf16 h = __float2bfloat16(f);
  return __builtin_bit_cast(unsigned short, h);
}

__device__ __forceinline__ void store_out(float* p, float v) { *p = v; }
__device__ __forceinline__ void store_out(bf16* p, float v) { *p = __float2bfloat16(v); }

// PV micro-op: D[m=q][n=d] += P(k=quad*4+0..3) * V(k=quad*4+0..3)
__device__ __forceinline__ f32x4 mfma16(bf16x4 a, bf16x4 b, f32x4 c) {
#if __has_builtin(__builtin_amdgcn_mfma_f32_16x16x16bf16_1k)
  return __builtin_amdgcn_mfma_f32_16x16x16bf16_1k(a, b, c, 0, 0, 0);
#else
  bf16x8 a8 = {a[0], a[1], a[2], a[3], 0, 0, 0, 0};
  bf16x8 b8 = {b[0], b[1], b[2], b[3], 0, 0, 0, 0};
  return __builtin_amdgcn_mfma_f32_16x16x32_bf16(a8, b8, c, 0, 0, 0);
#endif
}

// ------------------------------------------- convert all 4 W matrices, fused
__global__ __launch_bounds__(256) void convert_w4(
    const float* __restrict__ s0, bf16* __restrict__ d0,   // Wq  4096 blocks
    const float* __restrict__ s1, bf16* __restrict__ d1,   // Wk  1024 blocks
    const float* __restrict__ s2, bf16* __restrict__ d2,   // Wv  1024 blocks
    const float* __restrict__ s3, bf16* __restrict__ d3) { // Wp  4096 blocks
  const int bid = blockIdx.x;
  const float* src;
  bf16* dst;
  int base;
  if (bid < 4096)      { src = s0; dst = d0; base = 0; }
  else if (bid < 5120) { src = s1; dst = d1; base = 4096; }
  else if (bid < 6144) { src = s2; dst = d2; base = 5120; }
  else                 { src = s3; dst = d3; base = 6144; }
  const int i = (bid - base) * 256 + threadIdx.x;  // sizes are exact multiples
  float4 v = ((const float4*)src)[i];
  ushort4 u;
  u.x = bfbits(v.x); u.y = bfbits(v.y); u.z = bfbits(v.z); u.w = bfbits(v.w);
  ((ushort4*)dst)[i] = u;
}

// ------------------------------------------------------- prep: rmsnorm + mix
__global__ __launch_bounds__(256) void prep(
    const float* __restrict__ x, const float* __restrict__ x0,
    const float* aq_p, const float* bq_p, const float* ak_p, const float* bk_p,
    bf16* __restrict__ xq, bf16* __restrict__ xk,
    bf16* __restrict__ xb, bf16* __restrict__ x0n) {
  const int row = blockIdx.x, tid = threadIdx.x;
  const float4* xr = (const float4*)(x + (size_t)row * Cc);
  const float4* nr = (const float4*)(x0 + (size_t)row * Cc);
  float4 xa[2], na[2];
  float ss = 0.f;
#pragma unroll
  for (int j = 0; j < 2; ++j) {
    xa[j] = xr[tid + j * 256];
    na[j] = nr[tid + j * 256];
    ss += na[j].x * na[j].x + na[j].y * na[j].y + na[j].z * na[j].z + na[j].w * na[j].w;
  }
#pragma unroll
  for (int o = 32; o; o >>= 1) ss += __shfl_xor(ss, o);
  __shared__ float red[4];
  if ((tid & 63) == 0) red[tid >> 6] = ss;
  __syncthreads();
  const float rms = rsqrtf((red[0] + red[1] + red[2] + red[3]) * (1.f / Cc) + EPS);
  const float aq = *aq_p, bq = *bq_p, ak = *ak_p, bk = *bk_p;
#pragma unroll
  for (int j = 0; j < 2; ++j) {
    const size_t base = (size_t)row * Cc + (size_t)(tid + j * 256) * 4;
    float nx[4] = {na[j].x * rms, na[j].y * rms, na[j].z * rms, na[j].w * rms};
    float xv[4] = {xa[j].x, xa[j].y, xa[j].z, xa[j].w};
    ushort4 uq, uk, ub, un;
    uq.x = bfbits(aq * xv[0] + bq * nx[0]); uq.y = bfbits(aq * xv[1] + bq * nx[1]);
    uq.z = bfbits(aq * xv[2] + bq * nx[2]); uq.w = bfbits(aq * xv[3] + bq * nx[3]);
    uk.x = bfbits(ak * xv[0] + bk * nx[0]); uk.y = bfbits(ak * xv[1] + bk * nx[1]);
    uk.z = bfbits(ak * xv[2] + bk * nx[2]); uk.w = bfbits(ak * xv[3] + bk * nx[3]);
    ub.x = bfbits(xv[0]); ub.y = bfbits(xv[1]); ub.z = bfbits(xv[2]); ub.w = bfbits(xv[3]);
    un.x = bfbits(nx[0]); un.y = bfbits(nx[1]); un.z = bfbits(nx[2]); un.w = bfbits(nx[3]);
    *(ushort4*)(xq + base) = uq;
    *(ushort4*)(xk + base) = uk;
    *(ushort4*)(xb + base) = ub;
    *(ushort4*)(x0n + base) = un;
  }
}

// ------------------------------------------------ GEMM body (m97 structure)
template <typename OutT>
__device__ __forceinline__ void gemm_body(
    const bf16* __restrict__ A, const bf16* __restrict__ W,
    OutT* __restrict__ C, int N, int K) {
  __shared__ unsigned short sA[128 * 64];
  __shared__ unsigned short sB[128 * 64];
  const int tid = threadIdx.x, wave = tid >> 6, lane = tid & 63;
  const int quad = lane >> 4, l15 = lane & 15;
  const int bm = blockIdx.x * 128, bn = blockIdx.y * 128;
  const int wm = (wave >> 1) * 64, wn = (wave & 1) * 64;
  const int srow = wave * 32 + (lane >> 3);
  const int scol = (lane & 7) * 8;

  f32x4 acc[4][4] = {};

  for (int k0 = 0; k0 < K; k0 += 64) {
#pragma unroll
    for (int i = 0; i < 4; ++i) {
      gld16(&sA[(wave * 32 + i * 8) * 64], &A[(size_t)(bm + srow + i * 8) * K + k0 + scol]);
      gld16(&sB[(wave * 32 + i * 8) * 64], &W[(size_t)(bn + srow + i * 8) * K + k0 + scol]);
    }
    __syncthreads();
#pragma unroll
    for (int kk = 0; kk < 2; ++kk) {
      bf16x8 af[4], bfr[4];
#pragma unroll
      for (int t = 0; t < 4; ++t)
        af[t] = *(const bf16x8*)&sA[(wm + t * 16 + l15) * 64 + kk * 32 + quad * 8];
#pragma unroll
      for (int t = 0; t < 4; ++t)
        bfr[t] = *(const bf16x8*)&sB[(wn + t * 16 + l15) * 64 + kk * 32 + quad * 8];
#pragma unroll
      for (int tm = 0; tm < 4; ++tm)
#pragma unroll
        for (int tn = 0; tn < 4; ++tn)
          acc[tm][tn] = __builtin_amdgcn_mfma_f32_16x16x32_bf16(af[tm], bfr[tn], acc[tm][tn], 0, 0, 0);
    }
    __syncthreads();
  }
#pragma unroll
  for (int tm = 0; tm < 4; ++tm)
#pragma unroll
    for (int tn = 0; tn < 4; ++tn)
#pragma unroll
      for (int r = 0; r < 4; ++r) {
        const int row = bm + wm + tm * 16 + quad * 4 + r;
        const int col = bn + wn + tn * 16 + l15;
        store_out(&C[(size_t)row * N + col], acc[tm][tn][r]);
      }
}

template <typename OutT>
__global__ __launch_bounds__(256) void gemm_bt(
    const bf16* __restrict__ A, const bf16* __restrict__ W,
    OutT* __restrict__ C, int N, int K) {
  gemm_body<OutT>(A, W, C, N, K);
}

struct GemmTriple { const bf16* A; const bf16* W; bf16* C; };
struct GemmTriple3 { GemmTriple t[3]; };

__global__ __launch_bounds__(256) void gemm_bt3(GemmTriple3 g, int N, int K) {
  const GemmTriple tr = g.t[blockIdx.z];
  gemm_body<bf16>(tr.A, tr.W, tr.C, N, K);
}

// ----------------- rope + per-head rmsnorm * mult, Q and K fused in one grid
__global__ __launch_bounds__(256) void post_qk2(
    const bf16* __restrict__ qpre, const bf16* __restrict__ kpre,
    const float* __restrict__ cosp, const float* __restrict__ sinp,
    bf16* __restrict__ qh, bf16* __restrict__ kh, float qmult) {
  int bid = blockIdx.x;
  const bf16* pre;
  bf16* outh;
  int nh;
  float mult;
  if (bid < 32768) { pre = qpre; outh = qh; nh = NH; mult = qmult; }
  else { bid -= 32768; pre = kpre; outh = kh; nh = NKV; mult = 1.2f; }
  const int wid = bid * 4 + (threadIdx.x >> 6);
  const int lane = threadIdx.x & 63;
  const int h = wid % nh;
  const int bt = wid / nh;
  const int t = bt & (Ts - 1);
  const int b = bt >> 11;
  const size_t src = (size_t)bt * (size_t)(nh * Dh) + (size_t)h * Dh;
  float x1 = __bfloat162float(pre[src + lane]);
  float x2 = __bfloat162float(pre[src + 64 + lane]);
  float c = cosp[t * 64 + lane], s = sinp[t * 64 + lane];
  float o1 = x1 * c + x2 * s;
  float o2 = x2 * c - x1 * s;
  float ss = o1 * o1 + o2 * o2;
#pragma unroll
  for (int o = 32; o; o >>= 1) ss += __shfl_xor(ss, o);
  const float r = rsqrtf(ss * (1.f / Dh) + EPS) * mult;
  const size_t dst = ((size_t)(b * nh + h) * Ts + t) * Dh;
  outh[dst + lane] = __float2bfloat16(o1 * r);
  outh[dst + 64 + lane] = __float2bfloat16(o2 * r);
}

// ------------------------- v mix + transpose to [b][hk][d][t]; v_init -> out
__global__ __launch_bounds__(256) void post_v(
    const bf16* __restrict__ vinit, const bf16* __restrict__ cvx,
    const float* av_p, const float* bv_p,
    bf16* __restrict__ vth, float* __restrict__ vout) {
  __shared__ unsigned short vt[128 * 65];
  const int t0 = blockIdx.x * 64;
  const int b = blockIdx.y >> 2, hk = blockIdx.y & 3;
  const float av = *av_p, bv = *bv_p;
  const int tid = threadIdx.x;
  for (int j = 0; j < 32; ++j) {
    const int e = j * 256 + tid;
    const int tl = e >> 7, d = e & 127;
    const size_t src = (size_t)(b * Ts + t0 + tl) * (NKV * Dh) + hk * Dh + d;
    const float vi = __bfloat162float(vinit[src]);
    const float cv = __bfloat162float(cvx[src]);
    vout[src] = vi;
    vt[d * 65 + tl] = bfbits(av * vi + bv * cv);
  }
  __syncthreads();
#pragma unroll
  for (int j = 0; j < 4; ++j) {
    const int g = j * 256 + tid;
    const int d = g >> 3, t8 = (g & 7) * 8;
    const unsigned short* p = &vt[d * 65 + t8];
    uint4 u;
    u.x = p[0] | ((unsigned int)p[1] << 16);
    u.y = p[2] | ((unsigned int)p[3] << 16);
    u.z = p[4] | ((unsigned int)p[5] << 16);
    u.w = p[6] | ((unsigned int)p[7] << 16);
    *(uint4*)&vth[((size_t)(b * NKV + hk) * Dh + d) * Ts + t0 + t8] = u;
  }
}

// -------------------------------------------------------- flash attention v2
// S^T = mfma(kf, qf): lane l15 = q, quad*4+r = j  -> P is directly the
// A-fragment of 16x16x16 PV MFMA. Softmax state per-lane.
// R7 core: fused per-tn streaming. Fixed optimistic reference max M0=12
// (softmax is shift-invariant; any finite reference works as long as
// exp2(s-M0) neither overflows (s-M0 < 127, trivially true) nor flushes
// meaningful mass (s-M0 > -126 for any s within 100 of the true max)).
// p = exp2(s - m_i) computed immediately per tn, packed to bf16, PV'd.
// If a tile raises the max by >8 (rare; never at M0=12 for N(0,2) scores),
// rescale of, l, m AFTER the tile -- uniform-correct since every prior
// contribution (incl. this tile's PV) shares the m_old reference.
// Transients: 1 kf (4) + s[2] (8) + pf[2] (4) + vf (2) -> VGPR fits 128,
// launch_bounds(256,4) enforces -> 4 waves/SIMD (was 3 at VGPR=152).
__global__ __launch_bounds__(256, 4) void attn(
    const bf16* __restrict__ qh, const bf16* __restrict__ kh,
    const bf16* __restrict__ vth, bf16* __restrict__ att) {
  __shared__ unsigned short sK[64 * 128];  // [j][d], 16B-granule XOR-swizzled by (j&15)
  __shared__ unsigned short sV[128 * 64];  // [d][j], 16B-granule XOR-swizzled by (d&7)

  const int tid = threadIdx.x, wave = tid >> 6, lane = tid & 63;
  const int quad = lane >> 4, l15 = lane & 15;
  // bijective XCD swizzle: nwg = 16*64 = 1024 = 8 XCDs x 128-block chunks.
  const int lin = blockIdx.y * 16 + blockIdx.x;
  const int swz = (lin & 7) * 128 + (lin >> 3);
  const int q0 = (swz & 15) * 128;
  const int by = swz >> 4;
  const int b = by >> 4, h = by & 15, hk = h >> 2;

  const bf16* Qp = qh + (size_t)(b * NH + h) * Ts * Dh;
  const bf16* Kp = kh + (size_t)(b * NKV + hk) * Ts * Dh;
  const bf16* Vp = vth + (size_t)(b * NKV + hk) * Dh * Ts;

  const int qw = q0 + wave * 32;

  // Q fragments straight from global (read once per block).
  bf16x8 qf[2][4];
#pragma unroll
  for (int tm = 0; tm < 2; ++tm)
#pragma unroll
    for (int kk = 0; kk < 4; ++kk)
      qf[tm][kk] = *(const bf16x8*)&Qp[(size_t)(qw + tm * 16 + l15) * Dh + kk * 32 + quad * 8];

  f32x4 of[2][8] = {};
  float m_i[2] = {12.f, 12.f};  // optimistic reference max M0
  float l_i[2] = {0.f, 0.f};

  const int krow = lane >> 4, kgp = lane & 15;  // K staging: 4 rows x 16 granules / 1KB
  const int vrow = lane >> 3, vgp = lane & 7;   // V staging: 8 rows x 8 granules / 1KB

  const int jt_lo = q0 >= WIN ? (q0 - WIN) >> 6 : 0;
  const int jt_hi = (q0 + 127) >> 6;

  for (int jt = jt_lo; jt <= jt_hi; ++jt) {
    const int j0 = jt << 6;
    __syncthreads();
#pragma unroll
    for (int i = 0; i < 4; ++i) {
      const int row = wave * 16 + i * 4 + krow;
      gld16(&sK[(wave * 16 + i * 4) * 128],
            &Kp[(size_t)(j0 + row) * Dh + (kgp ^ (row & 15)) * 8]);
      const int d = wave * 32 + i * 8 + vrow;
      gld16(&sV[(wave * 32 + i * 8) * 64],
            &Vp[(size_t)d * Ts + j0 + (vgp ^ (d & 7)) * 8]);
    }
    __syncthreads();

    // per-wave skip of fully-masked tiles (barrier counts stay uniform)
    if (j0 > qw + 31 || qw > j0 + 63 + WIN) continue;

    // wave-uniform: every row of this wave sees a fully-unmasked tile?
    const bool full = (j0 + 63 <= qw) && (qw + 31 - j0 <= WIN);

    float mloc[2] = {-__builtin_inff(), -__builtin_inff()};
    float rs[2] = {0.f, 0.f};

#pragma unroll
    for (int tn = 0; tn < 4; ++tn) {
      // QK^T for this j-subtile, one kf live at a time
      f32x4 s[2] = {};
#pragma unroll
      for (int kk = 0; kk < 4; ++kk) {
        const bf16x8 kf = *(const bf16x8*)&sK[(tn * 16 + l15) * 128 + (((kk * 4 + quad) ^ l15) * 8)];
#pragma unroll
        for (int tm = 0; tm < 2; ++tm)
          s[tm] = __builtin_amdgcn_mfma_f32_16x16x32_bf16(kf, qf[tm][kk], s[tm], 0, 0, 0);
      }
      // mask + optimistic exp + pack (streaming: no S^T array kept)
      bf16x4 pf[2];
#pragma unroll
      for (int tm = 0; tm < 2; ++tm) {
        if (!full) {
          const int dq = (qw + tm * 16 + l15) - (j0 + tn * 16 + quad * 4);  // q - j at r=0
#pragma unroll
          for (int r = 0; r < 4; ++r)
            if ((unsigned)(dq - r) > (unsigned)WIN) s[tm][r] = -__builtin_inff();
        }
#pragma unroll
        for (int r = 0; r < 4; ++r) {
          const float sv = s[tm][r];
          mloc[tm] = fmaxf(mloc[tm], sv);
          const float p = __builtin_amdgcn_exp2f(sv - m_i[tm]);  // exp2(-inf)=0
          rs[tm] += p;
          pf[tm][r] = (short)bfbits(p);
        }
      }
      // PV for this tn immediately; P never leaves registers
      const int gsw = (tn * 2) ^ (l15 & 7);
#pragma unroll
      for (int dn = 0; dn < 8; ++dn) {
        const int d = dn * 16 + l15;
        const bf16x4 vf = *(const bf16x4*)&sV[d * 64 + ((gsw ^ (quad >> 1)) * 8) + (quad & 1) * 4];
        of[0][dn] = mfma16(pf[0], vf, of[0][dn]);
        of[1][dn] = mfma16(pf[1], vf, of[1][dn]);
      }
    }

    // tile finalize: cross-quad reductions + rare deferred rescale
#pragma unroll
    for (int tm = 0; tm < 2; ++tm) {
      float mg = fmaxf(mloc[tm], __shfl_xor(mloc[tm], 16));
      mg = fmaxf(mg, __shfl_xor(mg, 32));
      float r2 = rs[tm] + __shfl_xor(rs[tm], 16);
      r2 += __shfl_xor(r2, 32);
      if (__all(mg - m_i[tm] <= 8.f)) {
        l_i[tm] += r2;
      } else {
        const float mnew = fmaxf(m_i[tm], mg);
        const float alpha = __builtin_amdgcn_exp2f(m_i[tm] - mnew);
        l_i[tm] = (l_i[tm] + r2) * alpha;
        m_i[tm] = mnew;
        float ar[4];
#pragma unroll
        for (int r = 0; r < 4; ++r) ar[r] = __shfl(alpha, quad * 4 + r);
#pragma unroll
        for (int dn = 0; dn < 8; ++dn)
#pragma unroll
          for (int r = 0; r < 4; ++r) of[tm][dn][r] *= ar[r];
      }
    }
  }

  // epilogue: normalize by l (per-row via shuffle), write att [b][t][h][d]
#pragma unroll
  for (int tm = 0; tm < 2; ++tm) {
#pragma unroll
    for (int r = 0; r < 4; ++r) {
      const float lr = __shfl(l_i[tm], quad * 4 + r);
      const float inv = 1.f / lr;
      const int qr = qw + tm * 16 + quad * 4 + r;
      bf16* dst = att + (size_t)(b * Ts + qr) * (NH * Dh) + h * Dh;
#pragma unroll
      for (int dn = 0; dn < 8; ++dn)
        dst[dn * 16 + l15] = __float2bfloat16(of[tm][dn][r] * inv);
    }
  }
}

// ------------------------------------------------------------------ launch
extern "C" void kernel_launch(void* const* d_in, const int* in_sizes, int n_in,
                              void* d_out, int out_size, void* d_ws, size_t ws_size,
                              hipStream_t stream) {
  const float* x = (const float*)d_in[0];
  const float* x0 = (const float*)d_in[1];
  const float* cosp = (const float*)d_in[3];
  const float* sinp = (const float*)d_in[4];
  const float* Wq = (const float*)d_in[5];
  const float* Wk = (const float*)d_in[6];
  const float* Wv = (const float*)d_in[7];
  const float* Wp = (const float*)d_in[8];
  const float* aq = (const float*)d_in[9];
  const float* bq = (const float*)d_in[10];
  const float* ak = (const float*)d_in[11];
  const float* bk = (const float*)d_in[12];
  const float* av = (const float*)d_in[13];
  const float* bv = (const float*)d_in[14];

  char* ws = (char*)d_ws;
  const size_t MB = 1024ull * 1024;
  bf16* xq = (bf16*)(ws + 0 * MB);
  bf16* xk = (bf16*)(ws + 32 * MB);
  bf16* xb = (bf16*)(ws + 64 * MB);
  bf16* x0n = (bf16*)(ws + 96 * MB);
  bf16* vinit = (bf16*)(ws + 128 * MB);
  bf16* cvx = (bf16*)(ws + 136 * MB);
  bf16* Wqb = (bf16*)(ws + 144 * MB);
  bf16* Wkb = (bf16*)(ws + 152 * MB);
  bf16* Wvb = (bf16*)(ws + 154 * MB);
  bf16* Wpb = (bf16*)(ws + 156 * MB);
  bf16* att = xq;                     // reuse (xq dead after Q-GEMM)
  bf16* qh = xk;                      // reuse (xk dead after K-GEMM)
  bf16* kh = xb;                      // reuse (xb dead after V-GEMM)
  bf16* vth = (bf16*)(ws + 72 * MB);  // inside xb region

  float* y = (float*)d_out;
  float* vout = (float*)d_out + (size_t)Bb * Ts * Cc;
  bf16* q_pre = (bf16*)d_out;  // parked in y region (overwritten last)
  bf16* k_pre = (bf16*)vout;   // parked in v_init region (overwritten by post_v)

  convert_w4<<<10240, 256, 0, stream>>>(Wq, Wqb, Wk, Wkb, Wv, Wvb, Wp, Wpb);

  prep<<<8192, 256, 0, stream>>>(x, x0, aq, bq, ak, bk, xq, xk, xb, x0n);

  gemm_bt<bf16><<<dim3(64, 16), 256, 0, stream>>>(xq, Wqb, q_pre, 2048, 2048);

  GemmTriple3 g3;
  g3.t[0] = {xk, Wkb, k_pre};
  g3.t[1] = {xb, Wvb, vinit};
  g3.t[2] = {x0n, Wvb, cvx};
  gemm_bt3<<<dim3(64, 4, 3), 256, 0, stream>>>(g3, 512, 2048);

  // q scale folds rmsnorm*1.2, softmax 1/sqrt(D), and log2(e) for exp2-softmax
  const float qmult = 1.2f * 0.08838834764831845f * 1.4426950408889634f;
  post_qk2<<<40960, 256, 0, stream>>>(q_pre, k_pre, cosp, sinp, qh, kh, qmult);
  post_v<<<dim3(32, 16), 256, 0, stream>>>(vinit, cvx, av, bv, vth, vout);

  attn<<<dim3(16, 64), 256, 0, stream>>>(qh, kh, vth, att);

  gemm_bt<float><<<dim3(64, 16), 256, 0, stream>>>(att, Wpb, y, 2048, 2048);
}

// Round 6
// 735.911 us; speedup vs baseline: 1.5666x; 1.5666x over previous
//
#include <hip/hip_runtime.h>
#include <hip/hip_bf16.h>
#include <math.h>

// CausalSelfAttention fused pipeline for MI355X (gfx950).
// B=4 T=2048 C=2048 H=16 HK=4 D=128 WIN=1024.
// R2: S^T trick, register-resident P, XOR-swizzled K/V, 32KB LDS.
// R3/R5: explicit pipelines regressed (occupancy/restructure cost).
// R6: R0 skeleton + XCD swizzle (FETCH 68.7->24.7MB) + VALU cuts + launch
// fusions -> 787us total, attn 180us, VGPR 152. BEST.
// R7: launch_bounds(256,4) forced VGPR 64 -> massive scratch spill (FETCH
// 955MB, attn 539us). NEVER cap below persistent-state floor (~100 regs).
// R8: streaming per-tn softmax with NO reference max (exact: softmax is
// shift-invariant; |s| <= 23.5 log2-units -> p <= 2^23.5, l <= 2^33.5, all
// in f32/bf16 range; R7's passing run validated these numerics). Removes
// sfT/pf transients (~45 VGPR) and ~120 VALU ops/tile (fmax, max-reduce,
// defer, rescale). No launch_bounds force -- compiler picks VGPR; if <=128
// we get 4 waves/SIMD organically.

using bf16 = __hip_bfloat16;
typedef __attribute__((ext_vector_type(8))) short bf16x8;
typedef __attribute__((ext_vector_type(4))) short bf16x4;
typedef __attribute__((ext_vector_type(4))) float f32x4;

constexpr int Bb = 4, Ts = 2048, Cc = 2048, NH = 16, NKV = 4, Dh = 128, WIN = 1024;
constexpr float EPS = 1.1920929e-07f;

__device__ __forceinline__ void gld16(void* lds, const void* g) {
  __builtin_amdgcn_global_load_lds(
      (__attribute__((address_space(1))) unsigned int*)((void*)g),
      (__attribute__((address_space(3))) unsigned int*)lds, 16, 0, 0);
}

__device__ __forceinline__ unsigned short bfbits(float f) {
  bf16 h = __float2bfloat16(f);
  return __builtin_bit_cast(unsigned short, h);
}

__device__ __forceinline__ void store_out(float* p, float v) { *p = v; }
__device__ __forceinline__ void store_out(bf16* p, float v) { *p = __float2bfloat16(v); }

// PV micro-op: D[m=q][n=d] += P(k=quad*4+0..3) * V(k=quad*4+0..3)
__device__ __forceinline__ f32x4 mfma16(bf16x4 a, bf16x4 b, f32x4 c) {
#if __has_builtin(__builtin_amdgcn_mfma_f32_16x16x16bf16_1k)
  return __builtin_amdgcn_mfma_f32_16x16x16bf16_1k(a, b, c, 0, 0, 0);
#else
  bf16x8 a8 = {a[0], a[1], a[2], a[3], 0, 0, 0, 0};
  bf16x8 b8 = {b[0], b[1], b[2], b[3], 0, 0, 0, 0};
  return __builtin_amdgcn_mfma_f32_16x16x32_bf16(a8, b8, c, 0, 0, 0);
#endif
}

// ------------------------------------------- convert all 4 W matrices, fused
__global__ __launch_bounds__(256) void convert_w4(
    const float* __restrict__ s0, bf16* __restrict__ d0,   // Wq  4096 blocks
    const float* __restrict__ s1, bf16* __restrict__ d1,   // Wk  1024 blocks
    const float* __restrict__ s2, bf16* __restrict__ d2,   // Wv  1024 blocks
    const float* __restrict__ s3, bf16* __restrict__ d3) { // Wp  4096 blocks
  const int bid = blockIdx.x;
  const float* src;
  bf16* dst;
  int base;
  if (bid < 4096)      { src = s0; dst = d0; base = 0; }
  else if (bid < 5120) { src = s1; dst = d1; base = 4096; }
  else if (bid < 6144) { src = s2; dst = d2; base = 5120; }
  else                 { src = s3; dst = d3; base = 6144; }
  const int i = (bid - base) * 256 + threadIdx.x;  // sizes are exact multiples
  float4 v = ((const float4*)src)[i];
  ushort4 u;
  u.x = bfbits(v.x); u.y = bfbits(v.y); u.z = bfbits(v.z); u.w = bfbits(v.w);
  ((ushort4*)dst)[i] = u;
}

// ------------------------------------------------------- prep: rmsnorm + mix
__global__ __launch_bounds__(256) void prep(
    const float* __restrict__ x, const float* __restrict__ x0,
    const float* aq_p, const float* bq_p, const float* ak_p, const float* bk_p,
    bf16* __restrict__ xq, bf16* __restrict__ xk,
    bf16* __restrict__ xb, bf16* __restrict__ x0n) {
  const int row = blockIdx.x, tid = threadIdx.x;
  const float4* xr = (const float4*)(x + (size_t)row * Cc);
  const float4* nr = (const float4*)(x0 + (size_t)row * Cc);
  float4 xa[2], na[2];
  float ss = 0.f;
#pragma unroll
  for (int j = 0; j < 2; ++j) {
    xa[j] = xr[tid + j * 256];
    na[j] = nr[tid + j * 256];
    ss += na[j].x * na[j].x + na[j].y * na[j].y + na[j].z * na[j].z + na[j].w * na[j].w;
  }
#pragma unroll
  for (int o = 32; o; o >>= 1) ss += __shfl_xor(ss, o);
  __shared__ float red[4];
  if ((tid & 63) == 0) red[tid >> 6] = ss;
  __syncthreads();
  const float rms = rsqrtf((red[0] + red[1] + red[2] + red[3]) * (1.f / Cc) + EPS);
  const float aq = *aq_p, bq = *bq_p, ak = *ak_p, bk = *bk_p;
#pragma unroll
  for (int j = 0; j < 2; ++j) {
    const size_t base = (size_t)row * Cc + (size_t)(tid + j * 256) * 4;
    float nx[4] = {na[j].x * rms, na[j].y * rms, na[j].z * rms, na[j].w * rms};
    float xv[4] = {xa[j].x, xa[j].y, xa[j].z, xa[j].w};
    ushort4 uq, uk, ub, un;
    uq.x = bfbits(aq * xv[0] + bq * nx[0]); uq.y = bfbits(aq * xv[1] + bq * nx[1]);
    uq.z = bfbits(aq * xv[2] + bq * nx[2]); uq.w = bfbits(aq * xv[3] + bq * nx[3]);
    uk.x = bfbits(ak * xv[0] + bk * nx[0]); uk.y = bfbits(ak * xv[1] + bk * nx[1]);
    uk.z = bfbits(ak * xv[2] + bk * nx[2]); uk.w = bfbits(ak * xv[3] + bk * nx[3]);
    ub.x = bfbits(xv[0]); ub.y = bfbits(xv[1]); ub.z = bfbits(xv[2]); ub.w = bfbits(xv[3]);
    un.x = bfbits(nx[0]); un.y = bfbits(nx[1]); un.z = bfbits(nx[2]); un.w = bfbits(nx[3]);
    *(ushort4*)(xq + base) = uq;
    *(ushort4*)(xk + base) = uk;
    *(ushort4*)(xb + base) = ub;
    *(ushort4*)(x0n + base) = un;
  }
}

// ------------------------------------------------ GEMM body (m97 structure)
template <typename OutT>
__device__ __forceinline__ void gemm_body(
    const bf16* __restrict__ A, const bf16* __restrict__ W,
    OutT* __restrict__ C, int N, int K) {
  __shared__ unsigned short sA[128 * 64];
  __shared__ unsigned short sB[128 * 64];
  const int tid = threadIdx.x, wave = tid >> 6, lane = tid & 63;
  const int quad = lane >> 4, l15 = lane & 15;
  const int bm = blockIdx.x * 128, bn = blockIdx.y * 128;
  const int wm = (wave >> 1) * 64, wn = (wave & 1) * 64;
  const int srow = wave * 32 + (lane >> 3);
  const int scol = (lane & 7) * 8;

  f32x4 acc[4][4] = {};

  for (int k0 = 0; k0 < K; k0 += 64) {
#pragma unroll
    for (int i = 0; i < 4; ++i) {
      gld16(&sA[(wave * 32 + i * 8) * 64], &A[(size_t)(bm + srow + i * 8) * K + k0 + scol]);
      gld16(&sB[(wave * 32 + i * 8) * 64], &W[(size_t)(bn + srow + i * 8) * K + k0 + scol]);
    }
    __syncthreads();
#pragma unroll
    for (int kk = 0; kk < 2; ++kk) {
      bf16x8 af[4], bfr[4];
#pragma unroll
      for (int t = 0; t < 4; ++t)
        af[t] = *(const bf16x8*)&sA[(wm + t * 16 + l15) * 64 + kk * 32 + quad * 8];
#pragma unroll
      for (int t = 0; t < 4; ++t)
        bfr[t] = *(const bf16x8*)&sB[(wn + t * 16 + l15) * 64 + kk * 32 + quad * 8];
#pragma unroll
      for (int tm = 0; tm < 4; ++tm)
#pragma unroll
        for (int tn = 0; tn < 4; ++tn)
          acc[tm][tn] = __builtin_amdgcn_mfma_f32_16x16x32_bf16(af[tm], bfr[tn], acc[tm][tn], 0, 0, 0);
    }
    __syncthreads();
  }
#pragma unroll
  for (int tm = 0; tm < 4; ++tm)
#pragma unroll
    for (int tn = 0; tn < 4; ++tn)
#pragma unroll
      for (int r = 0; r < 4; ++r) {
        const int row = bm + wm + tm * 16 + quad * 4 + r;
        const int col = bn + wn + tn * 16 + l15;
        store_out(&C[(size_t)row * N + col], acc[tm][tn][r]);
      }
}

template <typename OutT>
__global__ __launch_bounds__(256) void gemm_bt(
    const bf16* __restrict__ A, const bf16* __restrict__ W,
    OutT* __restrict__ C, int N, int K) {
  gemm_body<OutT>(A, W, C, N, K);
}

struct GemmTriple { const bf16* A; const bf16* W; bf16* C; };
struct GemmTriple3 { GemmTriple t[3]; };

__global__ __launch_bounds__(256) void gemm_bt3(GemmTriple3 g, int N, int K) {
  const GemmTriple tr = g.t[blockIdx.z];
  gemm_body<bf16>(tr.A, tr.W, tr.C, N, K);
}

// ----------------- rope + per-head rmsnorm * mult, Q and K fused in one grid
__global__ __launch_bounds__(256) void post_qk2(
    const bf16* __restrict__ qpre, const bf16* __restrict__ kpre,
    const float* __restrict__ cosp, const float* __restrict__ sinp,
    bf16* __restrict__ qh, bf16* __restrict__ kh, float qmult) {
  int bid = blockIdx.x;
  const bf16* pre;
  bf16* outh;
  int nh;
  float mult;
  if (bid < 32768) { pre = qpre; outh = qh; nh = NH; mult = qmult; }
  else { bid -= 32768; pre = kpre; outh = kh; nh = NKV; mult = 1.2f; }
  const int wid = bid * 4 + (threadIdx.x >> 6);
  const int lane = threadIdx.x & 63;
  const int h = wid % nh;
  const int bt = wid / nh;
  const int t = bt & (Ts - 1);
  const int b = bt >> 11;
  const size_t src = (size_t)bt * (size_t)(nh * Dh) + (size_t)h * Dh;
  float x1 = __bfloat162float(pre[src + lane]);
  float x2 = __bfloat162float(pre[src + 64 + lane]);
  float c = cosp[t * 64 + lane], s = sinp[t * 64 + lane];
  float o1 = x1 * c + x2 * s;
  float o2 = x2 * c - x1 * s;
  float ss = o1 * o1 + o2 * o2;
#pragma unroll
  for (int o = 32; o; o >>= 1) ss += __shfl_xor(ss, o);
  const float r = rsqrtf(ss * (1.f / Dh) + EPS) * mult;
  const size_t dst = ((size_t)(b * nh + h) * Ts + t) * Dh;
  outh[dst + lane] = __float2bfloat16(o1 * r);
  outh[dst + 64 + lane] = __float2bfloat16(o2 * r);
}

// ------------------------- v mix + transpose to [b][hk][d][t]; v_init -> out
__global__ __launch_bounds__(256) void post_v(
    const bf16* __restrict__ vinit, const bf16* __restrict__ cvx,
    const float* av_p, const float* bv_p,
    bf16* __restrict__ vth, float* __restrict__ vout) {
  __shared__ unsigned short vt[128 * 65];
  const int t0 = blockIdx.x * 64;
  const int b = blockIdx.y >> 2, hk = blockIdx.y & 3;
  const float av = *av_p, bv = *bv_p;
  const int tid = threadIdx.x;
  for (int j = 0; j < 32; ++j) {
    const int e = j * 256 + tid;
    const int tl = e >> 7, d = e & 127;
    const size_t src = (size_t)(b * Ts + t0 + tl) * (NKV * Dh) + hk * Dh + d;
    const float vi = __bfloat162float(vinit[src]);
    const float cv = __bfloat162float(cvx[src]);
    vout[src] = vi;
    vt[d * 65 + tl] = bfbits(av * vi + bv * cv);
  }
  __syncthreads();
#pragma unroll
  for (int j = 0; j < 4; ++j) {
    const int g = j * 256 + tid;
    const int d = g >> 3, t8 = (g & 7) * 8;
    const unsigned short* p = &vt[d * 65 + t8];
    uint4 u;
    u.x = p[0] | ((unsigned int)p[1] << 16);
    u.y = p[2] | ((unsigned int)p[3] << 16);
    u.z = p[4] | ((unsigned int)p[5] << 16);
    u.w = p[6] | ((unsigned int)p[7] << 16);
    *(uint4*)&vth[((size_t)(b * NKV + hk) * Dh + d) * Ts + t0 + t8] = u;
  }
}

// -------------------------------------------------------- flash attention v2
// S^T = mfma(kf, qf): lane l15 = q, quad*4+r = j  -> P is directly the
// A-fragment of 16x16x16 PV MFMA. Softmax with NO reference max:
// p = exp2(s) directly. Exact by shift-invariance; bounded because
// |s| <= ||q||*||k||*scale*log2e = 1.44*128*0.0884*1.4427 = 23.5 log2-units
// -> p <= 2^23.5 (bf16 ok), l <= 1024*2^23.5 = 2^33.5 (f32 ok),
// of <= l*|v|max (f32 ok). Masked s = -inf -> exp2 = 0.
// l accumulated per-lane (f32x4, 4 indep chains), reduced ONCE in epilogue.
// R6 skeleton otherwise: 32KB single-buffer, stage-then-drain, 2 barriers/
// tile, XCD-chunked swizzle. No launch_bounds force (R7 spill lesson).
__global__ __launch_bounds__(256) void attn(
    const bf16* __restrict__ qh, const bf16* __restrict__ kh,
    const bf16* __restrict__ vth, bf16* __restrict__ att) {
  __shared__ unsigned short sK[64 * 128];  // [j][d], 16B-granule XOR-swizzled by (j&15)
  __shared__ unsigned short sV[128 * 64];  // [d][j], 16B-granule XOR-swizzled by (d&7)

  const int tid = threadIdx.x, wave = tid >> 6, lane = tid & 63;
  const int quad = lane >> 4, l15 = lane & 15;
  // bijective XCD swizzle: nwg = 16*64 = 1024 = 8 XCDs x 128-block chunks.
  const int lin = blockIdx.y * 16 + blockIdx.x;
  const int swz = (lin & 7) * 128 + (lin >> 3);
  const int q0 = (swz & 15) * 128;
  const int by = swz >> 4;
  const int b = by >> 4, h = by & 15, hk = h >> 2;

  const bf16* Qp = qh + (size_t)(b * NH + h) * Ts * Dh;
  const bf16* Kp = kh + (size_t)(b * NKV + hk) * Ts * Dh;
  const bf16* Vp = vth + (size_t)(b * NKV + hk) * Dh * Ts;

  const int qw = q0 + wave * 32;

  // Q fragments straight from global (read once per block).
  bf16x8 qf[2][4];
#pragma unroll
  for (int tm = 0; tm < 2; ++tm)
#pragma unroll
    for (int kk = 0; kk < 4; ++kk)
      qf[tm][kk] = *(const bf16x8*)&Qp[(size_t)(qw + tm * 16 + l15) * Dh + kk * 32 + quad * 8];

  f32x4 of[2][8] = {};
  f32x4 l4[2] = {};  // per-lane partial row-sums, 4 independent chains

  const int krow = lane >> 4, kgp = lane & 15;  // K staging: 4 rows x 16 granules / 1KB
  const int vrow = lane >> 3, vgp = lane & 7;   // V staging: 8 rows x 8 granules / 1KB

  const int jt_lo = q0 >= WIN ? (q0 - WIN) >> 6 : 0;
  const int jt_hi = (q0 + 127) >> 6;

  for (int jt = jt_lo; jt <= jt_hi; ++jt) {
    const int j0 = jt << 6;
    __syncthreads();
#pragma unroll
    for (int i = 0; i < 4; ++i) {
      const int row = wave * 16 + i * 4 + krow;
      gld16(&sK[(wave * 16 + i * 4) * 128],
            &Kp[(size_t)(j0 + row) * Dh + (kgp ^ (row & 15)) * 8]);
      const int d = wave * 32 + i * 8 + vrow;
      gld16(&sV[(wave * 32 + i * 8) * 64],
            &Vp[(size_t)d * Ts + j0 + (vgp ^ (d & 7)) * 8]);
    }
    __syncthreads();

    // per-wave skip of fully-masked tiles (barrier counts stay uniform)
    if (j0 > qw + 31 || qw > j0 + 63 + WIN) continue;

    // wave-uniform: every row of this wave sees a fully-unmasked tile?
    const bool full = (j0 + 63 <= qw) && (qw + 31 - j0 <= WIN);

#pragma unroll
    for (int tn = 0; tn < 4; ++tn) {
      // QK^T for this j-subtile, one kf live at a time
      f32x4 s[2] = {};
#pragma unroll
      for (int kk = 0; kk < 4; ++kk) {
        const bf16x8 kf = *(const bf16x8*)&sK[(tn * 16 + l15) * 128 + (((kk * 4 + quad) ^ l15) * 8)];
#pragma unroll
        for (int tm = 0; tm < 2; ++tm)
          s[tm] = __builtin_amdgcn_mfma_f32_16x16x32_bf16(kf, qf[tm][kk], s[tm], 0, 0, 0);
      }
      // mask + direct exp (no reference max) + pack; P never leaves registers
      bf16x4 pf[2];
#pragma unroll
      for (int tm = 0; tm < 2; ++tm) {
        if (!full) {
          const int dq = (qw + tm * 16 + l15) - (j0 + tn * 16 + quad * 4);  // q - j at r=0
#pragma unroll
          for (int r = 0; r < 4; ++r)
            if ((unsigned)(dq - r) > (unsigned)WIN) s[tm][r] = -__builtin_inff();
        }
#pragma unroll
        for (int r = 0; r < 4; ++r) {
          const float p = __builtin_amdgcn_exp2f(s[tm][r]);
          l4[tm][r] += p;
          pf[tm][r] = (short)bfbits(p);
        }
      }
      // PV for this tn immediately
      const int gsw = (tn * 2) ^ (l15 & 7);
#pragma unroll
      for (int dn = 0; dn < 8; ++dn) {
        const int d = dn * 16 + l15;
        const bf16x4 vf = *(const bf16x4*)&sV[d * 64 + ((gsw ^ (quad >> 1)) * 8) + (quad & 1) * 4];
        of[0][dn] = mfma16(pf[0], vf, of[0][dn]);
        of[1][dn] = mfma16(pf[1], vf, of[1][dn]);
      }
    }
  }

  // epilogue: one l reduction (components + cross-quad), normalize, write att
#pragma unroll
  for (int tm = 0; tm < 2; ++tm) {
    float l = (l4[tm][0] + l4[tm][1]) + (l4[tm][2] + l4[tm][3]);
    l += __shfl_xor(l, 16);
    l += __shfl_xor(l, 32);
#pragma unroll
    for (int r = 0; r < 4; ++r) {
      const float lr = __shfl(l, quad * 4 + r);
      const float inv = 1.f / lr;
      const int qr = qw + tm * 16 + quad * 4 + r;
      bf16* dst = att + (size_t)(b * Ts + qr) * (NH * Dh) + h * Dh;
#pragma unroll
      for (int dn = 0; dn < 8; ++dn)
        dst[dn * 16 + l15] = __float2bfloat16(of[tm][dn][r] * inv);
    }
  }
}

// ------------------------------------------------------------------ launch
extern "C" void kernel_launch(void* const* d_in, const int* in_sizes, int n_in,
                              void* d_out, int out_size, void* d_ws, size_t ws_size,
                              hipStream_t stream) {
  const float* x = (const float*)d_in[0];
  const float* x0 = (const float*)d_in[1];
  const float* cosp = (const float*)d_in[3];
  const float* sinp = (const float*)d_in[4];
  const float* Wq = (const float*)d_in[5];
  const float* Wk = (const float*)d_in[6];
  const float* Wv = (const float*)d_in[7];
  const float* Wp = (const float*)d_in[8];
  const float* aq = (const float*)d_in[9];
  const float* bq = (const float*)d_in[10];
  const float* ak = (const float*)d_in[11];
  const float* bk = (const float*)d_in[12];
  const float* av = (const float*)d_in[13];
  const float* bv = (const float*)d_in[14];

  char* ws = (char*)d_ws;
  const size_t MB = 1024ull * 1024;
  bf16* xq = (bf16*)(ws + 0 * MB);
  bf16* xk = (bf16*)(ws + 32 * MB);
  bf16* xb = (bf16*)(ws + 64 * MB);
  bf16* x0n = (bf16*)(ws + 96 * MB);
  bf16* vinit = (bf16*)(ws + 128 * MB);
  bf16* cvx = (bf16*)(ws + 136 * MB);
  bf16* Wqb = (bf16*)(ws + 144 * MB);
  bf16* Wkb = (bf16*)(ws + 152 * MB);
  bf16* Wvb = (bf16*)(ws + 154 * MB);
  bf16* Wpb = (bf16*)(ws + 156 * MB);
  bf16* att = xq;                     // reuse (xq dead after Q-GEMM)
  bf16* qh = xk;                      // reuse (xk dead after K-GEMM)
  bf16* kh = xb;                      // reuse (xb dead after V-GEMM)
  bf16* vth = (bf16*)(ws + 72 * MB);  // inside xb region

  float* y = (float*)d_out;
  float* vout = (float*)d_out + (size_t)Bb * Ts * Cc;
  bf16* q_pre = (bf16*)d_out;  // parked in y region (overwritten last)
  bf16* k_pre = (bf16*)vout;   // parked in v_init region (overwritten by post_v)

  convert_w4<<<10240, 256, 0, stream>>>(Wq, Wqb, Wk, Wkb, Wv, Wvb, Wp, Wpb);

  prep<<<8192, 256, 0, stream>>>(x, x0, aq, bq, ak, bk, xq, xk, xb, x0n);

  gemm_bt<bf16><<<dim3(64, 16), 256, 0, stream>>>(xq, Wqb, q_pre, 2048, 2048);

  GemmTriple3 g3;
  g3.t[0] = {xk, Wkb, k_pre};
  g3.t[1] = {xb, Wvb, vinit};
  g3.t[2] = {x0n, Wvb, cvx};
  gemm_bt3<<<dim3(64, 4, 3), 256, 0, stream>>>(g3, 512, 2048);

  // q scale folds rmsnorm*1.2, softmax 1/sqrt(D), and log2(e) for exp2-softmax
  const float qmult = 1.2f * 0.08838834764831845f * 1.4426950408889634f;
  post_qk2<<<40960, 256, 0, stream>>>(q_pre, k_pre, cosp, sinp, qh, kh, qmult);
  post_v<<<dim3(32, 16), 256, 0, stream>>>(vinit, cvx, av, bv, vth, vout);

  attn<<<dim3(16, 64), 256, 0, stream>>>(qh, kh, vth, att);

  gemm_bt<float><<<dim3(64, 16), 256, 0, stream>>>(att, Wpb, y, 2048, 2048);
}

// Round 7
// 653.435 us; speedup vs baseline: 1.7643x; 1.1262x over previous
//
#include <hip/hip_runtime.h>
#include <hip/hip_bf16.h>
#include <math.h>

// CausalSelfAttention fused pipeline for MI355X (gfx950).
// B=4 T=2048 C=2048 H=16 HK=4 D=128 WIN=1024.
// R6: attn R0 skeleton + XCD swizzle + fusions -> 787us.
// R7: forced launch_bounds(256,4) -> VGPR 64 spill catastrophe (539us attn).
// R8: streaming no-reference-max softmax -> VGPR 128 organic, attn 121.6us,
// total 735.9us. BEST. GEMMs now dominate (126+122+~126 = ~375us at 546 TF,
// MfmaUtil 22%, 25M LDS bank conflicts).
// R9: GEMM rewritten to 256x256 tile, BK=64, 8 waves (2Mx4N), 128KB dbuf LDS,
// counted-vmcnt depth-2 pipeline (T3/T4: vmcnt(8) in steady state, loads stay
// in flight ACROSS barriers; never drain to 0 mid-loop), XOR-granule LDS
// swizzle (T2; same proven pattern as attn staging), raw s_barrier + asm
// waitcnt + sched_barrier (rule #18). 64 MFMA/wave/barrier-pair (2x m97).
// attn and all other kernels identical to R8.

using bf16 = __hip_bfloat16;
typedef __attribute__((ext_vector_type(8))) short bf16x8;
typedef __attribute__((ext_vector_type(4))) short bf16x4;
typedef __attribute__((ext_vector_type(4))) float f32x4;

constexpr int Bb = 4, Ts = 2048, Cc = 2048, NH = 16, NKV = 4, Dh = 128, WIN = 1024;
constexpr float EPS = 1.1920929e-07f;

__device__ __forceinline__ void gld16(void* lds, const void* g) {
  __builtin_amdgcn_global_load_lds(
      (__attribute__((address_space(1))) unsigned int*)((void*)g),
      (__attribute__((address_space(3))) unsigned int*)lds, 16, 0, 0);
}

__device__ __forceinline__ unsigned short bfbits(float f) {
  bf16 h = __float2bfloat16(f);
  return __builtin_bit_cast(unsigned short, h);
}

__device__ __forceinline__ void store_out(float* p, float v) { *p = v; }
__device__ __forceinline__ void store_out(bf16* p, float v) { *p = __float2bfloat16(v); }

// PV micro-op: D[m=q][n=d] += P(k=quad*4+0..3) * V(k=quad*4+0..3)
__device__ __forceinline__ f32x4 mfma16(bf16x4 a, bf16x4 b, f32x4 c) {
#if __has_builtin(__builtin_amdgcn_mfma_f32_16x16x16bf16_1k)
  return __builtin_amdgcn_mfma_f32_16x16x16bf16_1k(a, b, c, 0, 0, 0);
#else
  bf16x8 a8 = {a[0], a[1], a[2], a[3], 0, 0, 0, 0};
  bf16x8 b8 = {b[0], b[1], b[2], b[3], 0, 0, 0, 0};
  return __builtin_amdgcn_mfma_f32_16x16x32_bf16(a8, b8, c, 0, 0, 0);
#endif
}

// ------------------------------------------- convert all 4 W matrices, fused
__global__ __launch_bounds__(256) void convert_w4(
    const float* __restrict__ s0, bf16* __restrict__ d0,   // Wq  4096 blocks
    const float* __restrict__ s1, bf16* __restrict__ d1,   // Wk  1024 blocks
    const float* __restrict__ s2, bf16* __restrict__ d2,   // Wv  1024 blocks
    const float* __restrict__ s3, bf16* __restrict__ d3) { // Wp  4096 blocks
  const int bid = blockIdx.x;
  const float* src;
  bf16* dst;
  int base;
  if (bid < 4096)      { src = s0; dst = d0; base = 0; }
  else if (bid < 5120) { src = s1; dst = d1; base = 4096; }
  else if (bid < 6144) { src = s2; dst = d2; base = 5120; }
  else                 { src = s3; dst = d3; base = 6144; }
  const int i = (bid - base) * 256 + threadIdx.x;  // sizes are exact multiples
  float4 v = ((const float4*)src)[i];
  ushort4 u;
  u.x = bfbits(v.x); u.y = bfbits(v.y); u.z = bfbits(v.z); u.w = bfbits(v.w);
  ((ushort4*)dst)[i] = u;
}

// ------------------------------------------------------- prep: rmsnorm + mix
__global__ __launch_bounds__(256) void prep(
    const float* __restrict__ x, const float* __restrict__ x0,
    const float* aq_p, const float* bq_p, const float* ak_p, const float* bk_p,
    bf16* __restrict__ xq, bf16* __restrict__ xk,
    bf16* __restrict__ xb, bf16* __restrict__ x0n) {
  const int row = blockIdx.x, tid = threadIdx.x;
  const float4* xr = (const float4*)(x + (size_t)row * Cc);
  const float4* nr = (const float4*)(x0 + (size_t)row * Cc);
  float4 xa[2], na[2];
  float ss = 0.f;
#pragma unroll
  for (int j = 0; j < 2; ++j) {
    xa[j] = xr[tid + j * 256];
    na[j] = nr[tid + j * 256];
    ss += na[j].x * na[j].x + na[j].y * na[j].y + na[j].z * na[j].z + na[j].w * na[j].w;
  }
#pragma unroll
  for (int o = 32; o; o >>= 1) ss += __shfl_xor(ss, o);
  __shared__ float red[4];
  if ((tid & 63) == 0) red[tid >> 6] = ss;
  __syncthreads();
  const float rms = rsqrtf((red[0] + red[1] + red[2] + red[3]) * (1.f / Cc) + EPS);
  const float aq = *aq_p, bq = *bq_p, ak = *ak_p, bk = *bk_p;
#pragma unroll
  for (int j = 0; j < 2; ++j) {
    const size_t base = (size_t)row * Cc + (size_t)(tid + j * 256) * 4;
    float nx[4] = {na[j].x * rms, na[j].y * rms, na[j].z * rms, na[j].w * rms};
    float xv[4] = {xa[j].x, xa[j].y, xa[j].z, xa[j].w};
    ushort4 uq, uk, ub, un;
    uq.x = bfbits(aq * xv[0] + bq * nx[0]); uq.y = bfbits(aq * xv[1] + bq * nx[1]);
    uq.z = bfbits(aq * xv[2] + bq * nx[2]); uq.w = bfbits(aq * xv[3] + bq * nx[3]);
    uk.x = bfbits(ak * xv[0] + bk * nx[0]); uk.y = bfbits(ak * xv[1] + bk * nx[1]);
    uk.z = bfbits(ak * xv[2] + bk * nx[2]); uk.w = bfbits(ak * xv[3] + bk * nx[3]);
    ub.x = bfbits(xv[0]); ub.y = bfbits(xv[1]); ub.z = bfbits(xv[2]); ub.w = bfbits(xv[3]);
    un.x = bfbits(nx[0]); un.y = bfbits(nx[1]); un.z = bfbits(nx[2]); un.w = bfbits(nx[3]);
    *(ushort4*)(xq + base) = uq;
    *(ushort4*)(xk + base) = uk;
    *(ushort4*)(xb + base) = ub;
    *(ushort4*)(x0n + base) = un;
  }
}

// ---------------------- GEMM 256x256, BK=64, 8 waves, dbuf + counted vmcnt
// Wave (wm,wn) = (wave>>2, wave&3) owns a 128x64 output sub-tile:
// acc[tm 0..7][tn 0..3] fragments of 16x16.
// LDS: sA/sB [2][256][64] ushort, XOR-granule swizzled: row r holds global
// granule g at slot g^(r&7) (source pre-swizzled at stage, read swizzled).
// Pipeline: stage(t) 2 tiles ahead; steady-state s_waitcnt vmcnt(8) -- the
// next tile's 8 loads stay in flight across both barriers (T4).
template <typename OutT>
__device__ __forceinline__ void gemm256_body(
    const bf16* __restrict__ A, const bf16* __restrict__ W,
    OutT* __restrict__ C, int N, int K, int bm, int bn) {
  __shared__ unsigned short sA[2][256 * 64];
  __shared__ unsigned short sB[2][256 * 64];
  const int tid = threadIdx.x, wave = tid >> 6, lane = tid & 63;
  const int quad = lane >> 4, l15 = lane & 15;
  const int wm = (wave >> 2) * 128, wn = (wave & 3) * 64;
  const int srow8 = lane >> 3;  // staging row within 8-row group
  const int sg = lane & 7;      // staging granule (pre-swizzle)

  f32x4 acc[8][4] = {};
  const int nt = K >> 6;

  auto stage = [&](int t, int buf) {
    const int k0 = t << 6;
#pragma unroll
    for (int i = 0; i < 4; ++i) {
      const int row = i * 64 + wave * 8 + srow8;  // per-lane row
      const int swz = (sg ^ (row & 7)) * 8;       // pre-swizzled source col
      gld16(&sA[buf][(i * 64 + wave * 8) * 64],
            &A[(size_t)(bm + row) * K + k0 + swz]);
      gld16(&sB[buf][(i * 64 + wave * 8) * 64],
            &W[(size_t)(bn + row) * K + k0 + swz]);
    }
  };

  stage(0, 0);
  stage(1, 1);
  asm volatile("s_waitcnt vmcnt(8)" ::: "memory");  // tile 0 landed
  __builtin_amdgcn_sched_barrier(0);
  __builtin_amdgcn_s_barrier();

  for (int t = 0; t < nt; ++t) {
    const unsigned short* a = sA[t & 1];
    const unsigned short* w = sB[t & 1];
#pragma unroll
    for (int kk = 0; kk < 2; ++kk) {
      const int gsw = ((kk * 4 + quad) ^ (l15 & 7)) * 8;
      bf16x8 af[8], bfr[4];
#pragma unroll
      for (int i = 0; i < 8; ++i)
        af[i] = *(const bf16x8*)&a[(wm + i * 16 + l15) * 64 + gsw];
#pragma unroll
      for (int i = 0; i < 4; ++i)
        bfr[i] = *(const bf16x8*)&w[(wn + i * 16 + l15) * 64 + gsw];
#pragma unroll
      for (int tm = 0; tm < 8; ++tm)
#pragma unroll
        for (int tn = 0; tn < 4; ++tn)
          acc[tm][tn] = __builtin_amdgcn_mfma_f32_16x16x32_bf16(af[tm], bfr[tn], acc[tm][tn], 0, 0, 0);
    }
    if (t == nt - 1) break;
    __builtin_amdgcn_s_barrier();  // all waves done reading buf[t&1]
    if (t + 2 < nt) {
      stage(t + 2, t & 1);         // overwrite the buffer just retired
      asm volatile("s_waitcnt vmcnt(8)" ::: "memory");  // tile t+1 landed;
                                                        // t+2 stays in flight
    } else {
      asm volatile("s_waitcnt vmcnt(0)" ::: "memory");  // final drain
    }
    __builtin_amdgcn_sched_barrier(0);
    __builtin_amdgcn_s_barrier();  // tile t+1 visible to all waves
  }

#pragma unroll
  for (int tm = 0; tm < 8; ++tm)
#pragma unroll
    for (int tn = 0; tn < 4; ++tn)
#pragma unroll
      for (int r = 0; r < 4; ++r) {
        const int row = bm + wm + tm * 16 + quad * 4 + r;
        const int col = bn + wn + tn * 16 + l15;
        store_out(&C[(size_t)row * N + col], acc[tm][tn][r]);
      }
}

template <typename OutT>
__global__ __launch_bounds__(512) void gemm_bt(
    const bf16* __restrict__ A, const bf16* __restrict__ W,
    OutT* __restrict__ C, int N, int K) {
  gemm256_body<OutT>(A, W, C, N, K, blockIdx.x * 256, blockIdx.y * 256);
}

struct GemmTriple { const bf16* A; const bf16* W; bf16* C; };
struct GemmTriple3 { GemmTriple t[3]; };

__global__ __launch_bounds__(512) void gemm_bt3(GemmTriple3 g, int N, int K) {
  const GemmTriple tr = g.t[blockIdx.z];
  gemm256_body<bf16>(tr.A, tr.W, tr.C, N, K, blockIdx.x * 256, blockIdx.y * 256);
}

// ----------------- rope + per-head rmsnorm * mult, Q and K fused in one grid
__global__ __launch_bounds__(256) void post_qk2(
    const bf16* __restrict__ qpre, const bf16* __restrict__ kpre,
    const float* __restrict__ cosp, const float* __restrict__ sinp,
    bf16* __restrict__ qh, bf16* __restrict__ kh, float qmult) {
  int bid = blockIdx.x;
  const bf16* pre;
  bf16* outh;
  int nh;
  float mult;
  if (bid < 32768) { pre = qpre; outh = qh; nh = NH; mult = qmult; }
  else { bid -= 32768; pre = kpre; outh = kh; nh = NKV; mult = 1.2f; }
  const int wid = bid * 4 + (threadIdx.x >> 6);
  const int lane = threadIdx.x & 63;
  const int h = wid % nh;
  const int bt = wid / nh;
  const int t = bt & (Ts - 1);
  const int b = bt >> 11;
  const size_t src = (size_t)bt * (size_t)(nh * Dh) + (size_t)h * Dh;
  float x1 = __bfloat162float(pre[src + lane]);
  float x2 = __bfloat162float(pre[src + 64 + lane]);
  float c = cosp[t * 64 + lane], s = sinp[t * 64 + lane];
  float o1 = x1 * c + x2 * s;
  float o2 = x2 * c - x1 * s;
  float ss = o1 * o1 + o2 * o2;
#pragma unroll
  for (int o = 32; o; o >>= 1) ss += __shfl_xor(ss, o);
  const float r = rsqrtf(ss * (1.f / Dh) + EPS) * mult;
  const size_t dst = ((size_t)(b * nh + h) * Ts + t) * Dh;
  outh[dst + lane] = __float2bfloat16(o1 * r);
  outh[dst + 64 + lane] = __float2bfloat16(o2 * r);
}

// ------------------------- v mix + transpose to [b][hk][d][t]; v_init -> out
__global__ __launch_bounds__(256) void post_v(
    const bf16* __restrict__ vinit, const bf16* __restrict__ cvx,
    const float* av_p, const float* bv_p,
    bf16* __restrict__ vth, float* __restrict__ vout) {
  __shared__ unsigned short vt[128 * 65];
  const int t0 = blockIdx.x * 64;
  const int b = blockIdx.y >> 2, hk = blockIdx.y & 3;
  const float av = *av_p, bv = *bv_p;
  const int tid = threadIdx.x;
  for (int j = 0; j < 32; ++j) {
    const int e = j * 256 + tid;
    const int tl = e >> 7, d = e & 127;
    const size_t src = (size_t)(b * Ts + t0 + tl) * (NKV * Dh) + hk * Dh + d;
    const float vi = __bfloat162float(vinit[src]);
    const float cv = __bfloat162float(cvx[src]);
    vout[src] = vi;
    vt[d * 65 + tl] = bfbits(av * vi + bv * cv);
  }
  __syncthreads();
#pragma unroll
  for (int j = 0; j < 4; ++j) {
    const int g = j * 256 + tid;
    const int d = g >> 3, t8 = (g & 7) * 8;
    const unsigned short* p = &vt[d * 65 + t8];
    uint4 u;
    u.x = p[0] | ((unsigned int)p[1] << 16);
    u.y = p[2] | ((unsigned int)p[3] << 16);
    u.z = p[4] | ((unsigned int)p[5] << 16);
    u.w = p[6] | ((unsigned int)p[7] << 16);
    *(uint4*)&vth[((size_t)(b * NKV + hk) * Dh + d) * Ts + t0 + t8] = u;
  }
}

// -------------------------------------------------------- flash attention v2
// S^T = mfma(kf, qf): lane l15 = q, quad*4+r = j  -> P is directly the
// A-fragment of 16x16x16 PV MFMA. Softmax with NO reference max:
// p = exp2(s) directly (exact by shift-invariance; |s| <= 23.5 log2-units).
// l accumulated per-lane (f32x4), reduced ONCE in epilogue. R8-verified.
__global__ __launch_bounds__(256) void attn(
    const bf16* __restrict__ qh, const bf16* __restrict__ kh,
    const bf16* __restrict__ vth, bf16* __restrict__ att) {
  __shared__ unsigned short sK[64 * 128];  // [j][d], 16B-granule XOR-swizzled by (j&15)
  __shared__ unsigned short sV[128 * 64];  // [d][j], 16B-granule XOR-swizzled by (d&7)

  const int tid = threadIdx.x, wave = tid >> 6, lane = tid & 63;
  const int quad = lane >> 4, l15 = lane & 15;
  // bijective XCD swizzle: nwg = 16*64 = 1024 = 8 XCDs x 128-block chunks.
  const int lin = blockIdx.y * 16 + blockIdx.x;
  const int swz = (lin & 7) * 128 + (lin >> 3);
  const int q0 = (swz & 15) * 128;
  const int by = swz >> 4;
  const int b = by >> 4, h = by & 15, hk = h >> 2;

  const bf16* Qp = qh + (size_t)(b * NH + h) * Ts * Dh;
  const bf16* Kp = kh + (size_t)(b * NKV + hk) * Ts * Dh;
  const bf16* Vp = vth + (size_t)(b * NKV + hk) * Dh * Ts;

  const int qw = q0 + wave * 32;

  // Q fragments straight from global (read once per block).
  bf16x8 qf[2][4];
#pragma unroll
  for (int tm = 0; tm < 2; ++tm)
#pragma unroll
    for (int kk = 0; kk < 4; ++kk)
      qf[tm][kk] = *(const bf16x8*)&Qp[(size_t)(qw + tm * 16 + l15) * Dh + kk * 32 + quad * 8];

  f32x4 of[2][8] = {};
  f32x4 l4[2] = {};  // per-lane partial row-sums, 4 independent chains

  const int krow = lane >> 4, kgp = lane & 15;  // K staging: 4 rows x 16 granules / 1KB
  const int vrow = lane >> 3, vgp = lane & 7;   // V staging: 8 rows x 8 granules / 1KB

  const int jt_lo = q0 >= WIN ? (q0 - WIN) >> 6 : 0;
  const int jt_hi = (q0 + 127) >> 6;

  for (int jt = jt_lo; jt <= jt_hi; ++jt) {
    const int j0 = jt << 6;
    __syncthreads();
#pragma unroll
    for (int i = 0; i < 4; ++i) {
      const int row = wave * 16 + i * 4 + krow;
      gld16(&sK[(wave * 16 + i * 4) * 128],
            &Kp[(size_t)(j0 + row) * Dh + (kgp ^ (row & 15)) * 8]);
      const int d = wave * 32 + i * 8 + vrow;
      gld16(&sV[(wave * 32 + i * 8) * 64],
            &Vp[(size_t)d * Ts + j0 + (vgp ^ (d & 7)) * 8]);
    }
    __syncthreads();

    // per-wave skip of fully-masked tiles (barrier counts stay uniform)
    if (j0 > qw + 31 || qw > j0 + 63 + WIN) continue;

    // wave-uniform: every row of this wave sees a fully-unmasked tile?
    const bool full = (j0 + 63 <= qw) && (qw + 31 - j0 <= WIN);

#pragma unroll
    for (int tn = 0; tn < 4; ++tn) {
      // QK^T for this j-subtile, one kf live at a time
      f32x4 s[2] = {};
#pragma unroll
      for (int kk = 0; kk < 4; ++kk) {
        const bf16x8 kf = *(const bf16x8*)&sK[(tn * 16 + l15) * 128 + (((kk * 4 + quad) ^ l15) * 8)];
#pragma unroll
        for (int tm = 0; tm < 2; ++tm)
          s[tm] = __builtin_amdgcn_mfma_f32_16x16x32_bf16(kf, qf[tm][kk], s[tm], 0, 0, 0);
      }
      // mask + direct exp (no reference max) + pack; P never leaves registers
      bf16x4 pf[2];
#pragma unroll
      for (int tm = 0; tm < 2; ++tm) {
        if (!full) {
          const int dq = (qw + tm * 16 + l15) - (j0 + tn * 16 + quad * 4);  // q - j at r=0
#pragma unroll
          for (int r = 0; r < 4; ++r)
            if ((unsigned)(dq - r) > (unsigned)WIN) s[tm][r] = -__builtin_inff();
        }
#pragma unroll
        for (int r = 0; r < 4; ++r) {
          const float p = __builtin_amdgcn_exp2f(s[tm][r]);
          l4[tm][r] += p;
          pf[tm][r] = (short)bfbits(p);
        }
      }
      // PV for this tn immediately
      const int gsw = (tn * 2) ^ (l15 & 7);
#pragma unroll
      for (int dn = 0; dn < 8; ++dn) {
        const int d = dn * 16 + l15;
        const bf16x4 vf = *(const bf16x4*)&sV[d * 64 + ((gsw ^ (quad >> 1)) * 8) + (quad & 1) * 4];
        of[0][dn] = mfma16(pf[0], vf, of[0][dn]);
        of[1][dn] = mfma16(pf[1], vf, of[1][dn]);
      }
    }
  }

  // epilogue: one l reduction (components + cross-quad), normalize, write att
#pragma unroll
  for (int tm = 0; tm < 2; ++tm) {
    float l = (l4[tm][0] + l4[tm][1]) + (l4[tm][2] + l4[tm][3]);
    l += __shfl_xor(l, 16);
    l += __shfl_xor(l, 32);
#pragma unroll
    for (int r = 0; r < 4; ++r) {
      const float lr = __shfl(l, quad * 4 + r);
      const float inv = 1.f / lr;
      const int qr = qw + tm * 16 + quad * 4 + r;
      bf16* dst = att + (size_t)(b * Ts + qr) * (NH * Dh) + h * Dh;
#pragma unroll
      for (int dn = 0; dn < 8; ++dn)
        dst[dn * 16 + l15] = __float2bfloat16(of[tm][dn][r] * inv);
    }
  }
}

// ------------------------------------------------------------------ launch
extern "C" void kernel_launch(void* const* d_in, const int* in_sizes, int n_in,
                              void* d_out, int out_size, void* d_ws, size_t ws_size,
                              hipStream_t stream) {
  const float* x = (const float*)d_in[0];
  const float* x0 = (const float*)d_in[1];
  const float* cosp = (const float*)d_in[3];
  const float* sinp = (const float*)d_in[4];
  const float* Wq = (const float*)d_in[5];
  const float* Wk = (const float*)d_in[6];
  const float* Wv = (const float*)d_in[7];
  const float* Wp = (const float*)d_in[8];
  const float* aq = (const float*)d_in[9];
  const float* bq = (const float*)d_in[10];
  const float* ak = (const float*)d_in[11];
  const float* bk = (const float*)d_in[12];
  const float* av = (const float*)d_in[13];
  const float* bv = (const float*)d_in[14];

  char* ws = (char*)d_ws;
  const size_t MB = 1024ull * 1024;
  bf16* xq = (bf16*)(ws + 0 * MB);
  bf16* xk = (bf16*)(ws + 32 * MB);
  bf16* xb = (bf16*)(ws + 64 * MB);
  bf16* x0n = (bf16*)(ws + 96 * MB);
  bf16* vinit = (bf16*)(ws + 128 * MB);
  bf16* cvx = (bf16*)(ws + 136 * MB);
  bf16* Wqb = (bf16*)(ws + 144 * MB);
  bf16* Wkb = (bf16*)(ws + 152 * MB);
  bf16* Wvb = (bf16*)(ws + 154 * MB);
  bf16* Wpb = (bf16*)(ws + 156 * MB);
  bf16* att = xq;                     // reuse (xq dead after Q-GEMM)
  bf16* qh = xk;                      // reuse (xk dead after K-GEMM)
  bf16* kh = xb;                      // reuse (xb dead after V-GEMM)
  bf16* vth = (bf16*)(ws + 72 * MB);  // inside xb region

  float* y = (float*)d_out;
  float* vout = (float*)d_out + (size_t)Bb * Ts * Cc;
  bf16* q_pre = (bf16*)d_out;  // parked in y region (overwritten last)
  bf16* k_pre = (bf16*)vout;   // parked in v_init region (overwritten by post_v)

  convert_w4<<<10240, 256, 0, stream>>>(Wq, Wqb, Wk, Wkb, Wv, Wvb, Wp, Wpb);

  prep<<<8192, 256, 0, stream>>>(x, x0, aq, bq, ak, bk, xq, xk, xb, x0n);

  gemm_bt<bf16><<<dim3(32, 8), 512, 0, stream>>>(xq, Wqb, q_pre, 2048, 2048);

  GemmTriple3 g3;
  g3.t[0] = {xk, Wkb, k_pre};
  g3.t[1] = {xb, Wvb, vinit};
  g3.t[2] = {x0n, Wvb, cvx};
  gemm_bt3<<<dim3(32, 2, 3), 512, 0, stream>>>(g3, 512, 2048);

  // q scale folds rmsnorm*1.2, softmax 1/sqrt(D), and log2(e) for exp2-softmax
  const float qmult = 1.2f * 0.08838834764831845f * 1.4426950408889634f;
  post_qk2<<<40960, 256, 0, stream>>>(q_pre, k_pre, cosp, sinp, qh, kh, qmult);
  post_v<<<dim3(32, 16), 256, 0, stream>>>(vinit, cvx, av, bv, vth, vout);

  attn<<<dim3(16, 64), 256, 0, stream>>>(qh, kh, vth, att);

  gemm_bt<float><<<dim3(32, 8), 512, 0, stream>>>(att, Wpb, y, 2048, 2048);
}